// Round 1
// baseline (200.572 us; speedup 1.0000x reference)
//
#include <hip/hip_runtime.h>
#include <hip/hip_bf16.h>

// Problem constants: B=16, S=1024, D=768, DOUT=256
static constexpr float INV_TEMP = 0.03608439182435161f; // 1/sqrt(768)

typedef __attribute__((ext_vector_type(8))) short bf16x8;
typedef __attribute__((ext_vector_type(4))) float f32x4;
typedef __attribute__((ext_vector_type(8))) unsigned short u16x8;
typedef __attribute__((ext_vector_type(4))) unsigned short u16x4;

__device__ __forceinline__ unsigned short f2bf(float f) {
  unsigned u = __float_as_uint(f);
  u += 0x7fffu + ((u >> 16) & 1u);
  return (unsigned short)(u >> 16);
}

__device__ __forceinline__ void async_copy16(const void* g, void* lds) {
  __builtin_amdgcn_global_load_lds(
      (const __attribute__((address_space(1))) unsigned int*)g,
      (__attribute__((address_space(3))) unsigned int*)lds, 16, 0, 0);
}

// ---------------- pack kernels ----------------
__global__ __launch_bounds__(256) void pack_emb(const float* __restrict__ src,
                                                unsigned short* __restrict__ dst) {
  long i = ((long)blockIdx.x * 256 + threadIdx.x) * 8;
  float4 a = *(const float4*)(src + i);
  float4 b = *(const float4*)(src + i + 4);
  u16x8 v;
  v[0] = f2bf(a.x); v[1] = f2bf(a.y); v[2] = f2bf(a.z); v[3] = f2bf(a.w);
  v[4] = f2bf(b.x); v[5] = f2bf(b.y); v[6] = f2bf(b.z); v[7] = f2bf(b.w);
  *(u16x8*)(dst + i) = v;
}

// WT_cat[n][d] = Wsel[d][col];  n<768: Wq, n<1536: Wk, else Wv.  bias_cat[n].
__global__ __launch_bounds__(256) void pack_w(
    const int* __restrict__ isq_p,
    const float* qWq, const float* qbq, const float* qWk, const float* qbk,
    const float* qWv, const float* qbv,
    const float* dWq, const float* dbq, const float* dWk, const float* dbk,
    const float* dWv, const float* dbv,
    unsigned short* __restrict__ WT, float* __restrict__ bias) {
  const int n = blockIdx.x;  // 0..1791
  const int isq = *isq_p;
  const float* W; const float* bsrc; int col, srcN;
  if (n < 768)       { W = isq ? qWq : dWq; bsrc = isq ? qbq : dbq; col = n;        srcN = 768; }
  else if (n < 1536) { W = isq ? qWk : dWk; bsrc = isq ? qbk : dbk; col = n - 768;  srcN = 768; }
  else               { W = isq ? qWv : dWv; bsrc = isq ? qbv : dbv; col = n - 1536; srcN = 256; }
#pragma unroll
  for (int i = 0; i < 3; ++i) {
    int d = threadIdx.x + i * 256;
    WT[(long)n * 768 + d] = f2bf(W[(long)d * srcN + col]);
  }
  if (threadIdx.x == 0) bias[n] = bsrc[col];
}

// ---------------- generic A*B^T GEMM, 128x128 tile, 4 waves, BK=32 ----------------
// MODE 0: bf16 out, +bias[col]   (QK projection)
// MODE 1: bf16 out, +bias[row]   (V^T projection)
// MODE 2: f32 out, *scale        (logits / PV)
template <int MODE>
__global__ __launch_bounds__(256) void gemm_bt(
    const unsigned short* __restrict__ A, long lda, long strideA,
    const unsigned short* __restrict__ BT, long ldb, long strideB,
    void* __restrict__ Cv, long ldc, long strideC,
    const float* __restrict__ bias, float scale, int K) {
  __shared__ unsigned short Ab[2][128 * 32];
  __shared__ unsigned short Bb[2][128 * 32];
  const int tid = threadIdx.x, wid = tid >> 6, lane = tid & 63;
  const int bz = blockIdx.z;
  A  += (long)bz * strideA + (long)blockIdx.x * 128 * lda;
  BT += (long)bz * strideB + (long)blockIdx.y * 128 * ldb;
  const int srow = lane >> 2;        // row within 16-row chunk
  const int skk  = (lane & 3) * 8;   // k offset (8 bf16 = 16B)

  auto stage = [&](int buf, int kt) {
    const unsigned short* As = A + (long)kt * 32;
    const unsigned short* Bs = BT + (long)kt * 32;
#pragma unroll
    for (int i = 0; i < 2; ++i) {
      int c = wid * 2 + i;  // chunk 0..7, 16 rows each
      async_copy16(As + (long)(c * 16 + srow) * lda + skk, &Ab[buf][c * 512]);
      async_copy16(Bs + (long)(c * 16 + srow) * ldb + skk, &Bb[buf][c * 512]);
    }
  };

  f32x4 acc[4][4] = {};
  const int nk = K / 32;
  stage(0, 0);
  __syncthreads();
  int buf = 0;
  const int wr = wid >> 1, wc = wid & 1;
  const int fr = lane & 15, fq = lane >> 4;
  for (int kt = 0; kt < nk; ++kt) {
    if (kt + 1 < nk) stage(buf ^ 1, kt + 1);
    const unsigned short* Ap = &Ab[buf][(wr * 64 + fr) * 32 + fq * 8];
    const unsigned short* Bp = &Bb[buf][(wc * 64 + fr) * 32 + fq * 8];
    bf16x8 af[4], bfv[4];
#pragma unroll
    for (int mi = 0; mi < 4; ++mi) af[mi] = *(const bf16x8*)(Ap + mi * 16 * 32);
#pragma unroll
    for (int ni = 0; ni < 4; ++ni) bfv[ni] = *(const bf16x8*)(Bp + ni * 16 * 32);
#pragma unroll
    for (int mi = 0; mi < 4; ++mi)
#pragma unroll
      for (int ni = 0; ni < 4; ++ni)
        acc[mi][ni] = __builtin_amdgcn_mfma_f32_16x16x32_bf16(af[mi], bfv[ni], acc[mi][ni], 0, 0, 0);
    __syncthreads();
    buf ^= 1;
  }

  const long m0 = (long)blockIdx.x * 128 + wr * 64;
  const long n0 = (long)blockIdx.y * 128 + wc * 64;
#pragma unroll
  for (int mi = 0; mi < 4; ++mi) {
#pragma unroll
    for (int ni = 0; ni < 4; ++ni) {
      const long m = m0 + mi * 16 + fq * 4;
      const long n = n0 + ni * 16 + fr;
      f32x4 v = acc[mi][ni];
      if (MODE == 0) {
        unsigned short* C = (unsigned short*)Cv + (long)bz * strideC;
        const float bb = bias[n];
#pragma unroll
        for (int r = 0; r < 4; ++r) C[(m + r) * ldc + n] = f2bf(v[r] + bb);
      } else if (MODE == 1) {
        unsigned short* C = (unsigned short*)Cv + (long)bz * strideC;
#pragma unroll
        for (int r = 0; r < 4; ++r) C[(m + r) * ldc + n] = f2bf(v[r] + bias[m + r]);
      } else {
        float* C = (float*)Cv + (long)bz * strideC;
#pragma unroll
        for (int r = 0; r < 4; ++r) C[(m + r) * ldc + n] = v[r] * scale;
      }
    }
  }
}

// ---------------- masked row softmax (in-place on d_out attn) + bf16 copy ----------------
__global__ __launch_bounds__(256) void softmax_rows(float* __restrict__ attn,
                                                    const int* __restrict__ mask,
                                                    unsigned short* __restrict__ attn_bf) {
  const int row = blockIdx.x;  // b*1024 + q
  const int b = row >> 10;
  float* p = attn + (long)row * 1024;
  const int tid = threadIdx.x, lane = tid & 63, wid = tid >> 6;
  float4 v = ((const float4*)p)[tid];
  int4 mk = ((const int4*)(mask + b * 1024))[tid];
  v.x = mk.x ? v.x : -1e9f;
  v.y = mk.y ? v.y : -1e9f;
  v.z = mk.z ? v.z : -1e9f;
  v.w = mk.w ? v.w : -1e9f;
  float mx = fmaxf(fmaxf(v.x, v.y), fmaxf(v.z, v.w));
#pragma unroll
  for (int off = 32; off; off >>= 1) mx = fmaxf(mx, __shfl_xor(mx, off));
  __shared__ float red[4];
  if (lane == 0) red[wid] = mx;
  __syncthreads();
  mx = fmaxf(fmaxf(red[0], red[1]), fmaxf(red[2], red[3]));
  float e0 = __expf(v.x - mx), e1 = __expf(v.y - mx);
  float e2 = __expf(v.z - mx), e3 = __expf(v.w - mx);
  float s = e0 + e1 + e2 + e3;
#pragma unroll
  for (int off = 32; off; off >>= 1) s += __shfl_xor(s, off);
  __shared__ float red2[4];
  if (lane == 0) red2[wid] = s;
  __syncthreads();
  s = red2[0] + red2[1] + red2[2] + red2[3];
  const float inv = 1.0f / s;
  float4 o;
  o.x = e0 * inv; o.y = e1 * inv; o.z = e2 * inv; o.w = e3 * inv;
  ((float4*)p)[tid] = o;
  u16x4 ob;
  ob[0] = f2bf(o.x); ob[1] = f2bf(o.y); ob[2] = f2bf(o.z); ob[3] = f2bf(o.w);
  *(u16x4*)(attn_bf + (long)row * 1024 + tid * 4) = ob;
}

// ---------------- launch ----------------
extern "C" void kernel_launch(void* const* d_in, const int* in_sizes, int n_in,
                              void* d_out, int out_size, void* d_ws, size_t ws_size,
                              hipStream_t stream) {
  const float* emb = (const float*)d_in[0];
  const int* mask = (const int*)d_in[1];
  const int* isq = (const int*)d_in[2];
  const float* qWq = (const float*)d_in[3];  const float* qbq = (const float*)d_in[4];
  const float* qWk = (const float*)d_in[5];  const float* qbk = (const float*)d_in[6];
  const float* qWv = (const float*)d_in[7];  const float* qbv = (const float*)d_in[8];
  const float* dWq = (const float*)d_in[9];  const float* dbq = (const float*)d_in[10];
  const float* dWk = (const float*)d_in[11]; const float* dbk = (const float*)d_in[12];
  const float* dWv = (const float*)d_in[13]; const float* dbv = (const float*)d_in[14];

  char* ws = (char*)d_ws;
  unsigned short* emb_bf = (unsigned short*)ws;  ws += (size_t)16384 * 768 * 2;   // 25.2 MB
  unsigned short* WT     = (unsigned short*)ws;  ws += (size_t)1792 * 768 * 2;    // 2.75 MB
  float*          bias   = (float*)ws;           ws += (size_t)1792 * 4;          // 7 KB
  unsigned short* QK     = (unsigned short*)ws;  ws += (size_t)16384 * 1536 * 2;  // 50.3 MB
  unsigned short* VT     = (unsigned short*)ws;  ws += (size_t)256 * 16384 * 2;   // 8.4 MB
  unsigned short* attnbf = (unsigned short*)ws;  ws += (size_t)16 * 1024 * 1024 * 2; // 33.6 MB

  float* out = (float*)d_out;                       // [16,1024,256]
  float* attn = out + (size_t)16 * 1024 * 256;      // [16,1024,1024]

  hipLaunchKernelGGL(pack_emb, dim3(6144), dim3(256), 0, stream, emb, emb_bf);
  hipLaunchKernelGGL(pack_w, dim3(1792), dim3(256), 0, stream, isq,
                     qWq, qbq, qWk, qbk, qWv, qbv, dWq, dbq, dWk, dbk, dWv, dbv, WT, bias);
  // Q|K projection: [16384,1536] = emb_bf * WT^T + bias(col)
  hipLaunchKernelGGL((gemm_bt<0>), dim3(128, 12, 1), dim3(256), 0, stream,
                     emb_bf, 768L, 0L, WT, 768L, 0L, (void*)QK, 1536L, 0L, bias, 1.0f, 768);
  // V^T: [256,16384] = WvT * emb_bf^T + bias(row)
  hipLaunchKernelGGL((gemm_bt<1>), dim3(2, 128, 1), dim3(256), 0, stream,
                     WT + (size_t)1536 * 768, 768L, 0L, emb_bf, 768L, 0L,
                     (void*)VT, 16384L, 0L, bias + 1536, 1.0f, 768);
  // logits: per batch [1024,1024] = Q_b * K_b^T * invTemp  -> d_out attn region (f32)
  hipLaunchKernelGGL((gemm_bt<2>), dim3(8, 8, 16), dim3(256), 0, stream,
                     QK, 1536L, (long)1024 * 1536, QK + 768, 1536L, (long)1024 * 1536,
                     (void*)attn, 1024L, (long)1024 * 1024, nullptr, INV_TEMP, 768);
  hipLaunchKernelGGL(softmax_rows, dim3(16384), dim3(256), 0, stream, attn, mask, attnbf);
  // out: per batch [1024,256] = attn_bf * V_b^T  (V_b^T rows are VT[:, b*1024+k])
  hipLaunchKernelGGL((gemm_bt<2>), dim3(8, 2, 16), dim3(256), 0, stream,
                     attnbf, 1024L, (long)1024 * 1024, VT, 16384L, 1024L,
                     (void*)out, 256L, (long)1024 * 256, nullptr, 1.0f, 1024);
}

// Round 2
// 183.334 us; speedup vs baseline: 1.0940x; 1.0940x over previous
//
#include <hip/hip_runtime.h>
#include <hip/hip_bf16.h>

// Problem constants: B=16, S=1024, D=768, DOUT=256
static constexpr float INV_TEMP = 0.03608439182435161f; // 1/sqrt(768)

typedef __attribute__((ext_vector_type(8))) short bf16x8;
typedef __attribute__((ext_vector_type(4))) float f32x4;
typedef __attribute__((ext_vector_type(8))) unsigned short u16x8;
typedef __attribute__((ext_vector_type(4))) unsigned short u16x4;

__device__ __forceinline__ unsigned short f2bf(float f) {
  unsigned u = __float_as_uint(f);
  u += 0x7fffu + ((u >> 16) & 1u);
  return (unsigned short)(u >> 16);
}

__device__ __forceinline__ void async_copy16(const void* g, void* lds) {
  __builtin_amdgcn_global_load_lds(
      (const __attribute__((address_space(1))) unsigned int*)g,
      (__attribute__((address_space(3))) unsigned int*)lds, 16, 0, 0);
}

// ---------------- pack kernels ----------------
__global__ __launch_bounds__(256) void pack_emb(const float* __restrict__ src,
                                                unsigned short* __restrict__ dst) {
  long i = ((long)blockIdx.x * 256 + threadIdx.x) * 8;
  float4 a = *(const float4*)(src + i);
  float4 b = *(const float4*)(src + i + 4);
  u16x8 v;
  v[0] = f2bf(a.x); v[1] = f2bf(a.y); v[2] = f2bf(a.z); v[3] = f2bf(a.w);
  v[4] = f2bf(b.x); v[5] = f2bf(b.y); v[6] = f2bf(b.z); v[7] = f2bf(b.w);
  *(u16x8*)(dst + i) = v;
}

__global__ __launch_bounds__(256) void pack_w(
    const int* __restrict__ isq_p,
    const float* qWq, const float* qbq, const float* qWk, const float* qbk,
    const float* qWv, const float* qbv,
    const float* dWq, const float* dbq, const float* dWk, const float* dbk,
    const float* dWv, const float* dbv,
    unsigned short* __restrict__ WT, float* __restrict__ bias) {
  const int n = blockIdx.x;  // 0..1791
  const int isq = *isq_p;
  const float* W; const float* bsrc; int col, srcN;
  if (n < 768)       { W = isq ? qWq : dWq; bsrc = isq ? qbq : dbq; col = n;        srcN = 768; }
  else if (n < 1536) { W = isq ? qWk : dWk; bsrc = isq ? qbk : dbk; col = n - 768;  srcN = 768; }
  else               { W = isq ? qWv : dWv; bsrc = isq ? qbv : dbv; col = n - 1536; srcN = 256; }
#pragma unroll
  for (int i = 0; i < 3; ++i) {
    int d = threadIdx.x + i * 256;
    WT[(long)n * 768 + d] = f2bf(W[(long)d * srcN + col]);
  }
  if (threadIdx.x == 0) bias[n] = bsrc[col];
}

// ================= 256x256 8-phase GEMM (T2+T3+T4+T5) =================
// C[M,N] = A[M,K] * BT[N,K]^T.  BK=64, split into 2 K-subtiles of 32.
// LDS: [buf(2)][mat A/B(2)][ksub(2)][256 rows x 32 cols] bf16 = 128 KiB.
// Swizzle: slot' = slot ^ ((row>>1)&3)  (16B slots within a 64B row).
// Staging: tile t phase0 -> (t+1) B-ks1 into buf (t+1)&1;
//          phases 1,2,3 -> (t+2) {A-ks0, B-ks0, A-ks1} into buf t&1
//          (each region's last ds_read is >=1 barrier before its overwrite issue).
// vmcnt(6) at each tile end (3 half-tiles in flight); vmcnt(0) only at t==nk-2.
// MODE 0: bf16 out + bias[col].  MODE 2: f32 out * scale.
template <int MODE>
__global__ __launch_bounds__(512, 2) void gemm256(
    const unsigned short* __restrict__ A, long lda, long strideA,
    const unsigned short* __restrict__ BT, long ldb, long strideB,
    void* __restrict__ Cv, long ldc, long strideC,
    const float* __restrict__ bias, float scale, int K) {
  extern __shared__ unsigned short smem[];  // 8 regions of 8192 elems
  const int tid = threadIdx.x;
  const int wid = tid >> 6, lane = tid & 63;
  const int wr = wid >> 2, wc = wid & 3;   // 2 (M) x 4 (N) wave grid
  const int fr = lane & 15, fq = lane >> 4;
  const int bz = blockIdx.z;
  const unsigned short* Apan = A + (long)bz * strideA + (long)blockIdx.x * 256 * lda;
  const unsigned short* Bpan = BT + (long)bz * strideB + (long)blockIdx.y * 256 * ldb;
  const int nk = K >> 6;

  auto stage = [&](int tile, int mat, int ks, int buf) {
    const unsigned short* g = (mat ? Bpan : Apan) + (long)tile * 64 + ks * 32;
    const long ld = mat ? ldb : lda;
    unsigned short* d = smem + (((buf << 2) | (mat << 1) | ks) << 13);
#pragma unroll
    for (int i = 0; i < 2; ++i) {
      const int e = (tid + i * 512) * 8;     // elem offset in region
      const int row = e >> 5;                // 0..255
      const int sl = (e >> 3) & 3;           // 16B slot 0..3
      const int ss = sl ^ ((row >> 1) & 3);  // pre-swizzled source slot
      async_copy16(g + (long)row * ld + ss * 8, d + e);
    }
  };

  // per-lane read offset within a [256][32] region (swizzled)
  const int fro = fr * 32 + ((fq ^ ((fr >> 1) & 3)) << 3);
  const int awo = fro + (wr * 128) * 32;   // + m*16*32
  const int bwo = fro + (wc * 64) * 32;    // + n*16*32

  bf16x8 a[8];
  f32x4 acc[8][4];
#pragma unroll
  for (int m = 0; m < 8; ++m)
#pragma unroll
    for (int n = 0; n < 4; ++n) acc[m][n] = f32x4{0.f, 0.f, 0.f, 0.f};

  // ---- prologue: tile0 (4 halves) + tile1 (3 halves) ----
  stage(0, 0, 0, 0); stage(0, 1, 0, 0); stage(0, 0, 1, 0); stage(0, 1, 1, 0);
  if (nk > 1) {
    stage(1, 0, 0, 1); stage(1, 1, 0, 1); stage(1, 0, 1, 1);
    asm volatile("s_waitcnt vmcnt(6)" ::: "memory");
  } else {
    asm volatile("s_waitcnt vmcnt(0)" ::: "memory");
  }
  __builtin_amdgcn_sched_barrier(0);
  __builtin_amdgcn_s_barrier();

  for (int t = 0; t < nk; ++t) {
    const int p = t & 1;
    const unsigned short* A0 = smem + (((p << 2) | 0) << 13);
    const unsigned short* A1 = smem + (((p << 2) | 1) << 13);
    const unsigned short* B0 = smem + (((p << 2) | 2) << 13);
    const unsigned short* B1 = smem + (((p << 2) | 3) << 13);

    // ---- phase 0: ksub0, n-frags 0,1 ----
    {
#pragma unroll
      for (int m = 0; m < 8; ++m) a[m] = *(const bf16x8*)(A0 + awo + m * 512);
      bf16x8 b0 = *(const bf16x8*)(B0 + bwo + 0 * 512);
      bf16x8 b1 = *(const bf16x8*)(B0 + bwo + 1 * 512);
      if (t + 1 < nk) stage(t + 1, 1, 1, (t + 1) & 1);
      __builtin_amdgcn_s_barrier();
      asm volatile("s_waitcnt lgkmcnt(0)");
      __builtin_amdgcn_sched_barrier(0);
      __builtin_amdgcn_s_setprio(1);
#pragma unroll
      for (int m = 0; m < 8; ++m) {
        acc[m][0] = __builtin_amdgcn_mfma_f32_16x16x32_bf16(a[m], b0, acc[m][0], 0, 0, 0);
        acc[m][1] = __builtin_amdgcn_mfma_f32_16x16x32_bf16(a[m], b1, acc[m][1], 0, 0, 0);
      }
      __builtin_amdgcn_s_setprio(0);
      __builtin_amdgcn_sched_barrier(0);
      __builtin_amdgcn_s_barrier();
    }
    // ---- phase 1: ksub0, n-frags 2,3 ----
    {
      bf16x8 b2 = *(const bf16x8*)(B0 + bwo + 2 * 512);
      bf16x8 b3 = *(const bf16x8*)(B0 + bwo + 3 * 512);
      if (t + 2 < nk) stage(t + 2, 0, 0, p);
      __builtin_amdgcn_s_barrier();
      asm volatile("s_waitcnt lgkmcnt(0)");
      __builtin_amdgcn_sched_barrier(0);
      __builtin_amdgcn_s_setprio(1);
#pragma unroll
      for (int m = 0; m < 8; ++m) {
        acc[m][2] = __builtin_amdgcn_mfma_f32_16x16x32_bf16(a[m], b2, acc[m][2], 0, 0, 0);
        acc[m][3] = __builtin_amdgcn_mfma_f32_16x16x32_bf16(a[m], b3, acc[m][3], 0, 0, 0);
      }
      __builtin_amdgcn_s_setprio(0);
      __builtin_amdgcn_sched_barrier(0);
      __builtin_amdgcn_s_barrier();
    }
    // ---- phase 2: ksub1, n-frags 0,1 ----
    {
#pragma unroll
      for (int m = 0; m < 8; ++m) a[m] = *(const bf16x8*)(A1 + awo + m * 512);
      bf16x8 b0 = *(const bf16x8*)(B1 + bwo + 0 * 512);
      bf16x8 b1 = *(const bf16x8*)(B1 + bwo + 1 * 512);
      if (t + 2 < nk) stage(t + 2, 1, 0, p);
      __builtin_amdgcn_s_barrier();
      asm volatile("s_waitcnt lgkmcnt(0)");
      __builtin_amdgcn_sched_barrier(0);
      __builtin_amdgcn_s_setprio(1);
#pragma unroll
      for (int m = 0; m < 8; ++m) {
        acc[m][0] = __builtin_amdgcn_mfma_f32_16x16x32_bf16(a[m], b0, acc[m][0], 0, 0, 0);
        acc[m][1] = __builtin_amdgcn_mfma_f32_16x16x32_bf16(a[m], b1, acc[m][1], 0, 0, 0);
      }
      __builtin_amdgcn_s_setprio(0);
      __builtin_amdgcn_sched_barrier(0);
      __builtin_amdgcn_s_barrier();
    }
    // ---- phase 3: ksub1, n-frags 2,3 + tile-end counted vmcnt ----
    {
      bf16x8 b2 = *(const bf16x8*)(B1 + bwo + 2 * 512);
      bf16x8 b3 = *(const bf16x8*)(B1 + bwo + 3 * 512);
      if (t + 2 < nk) stage(t + 2, 0, 1, p);
      __builtin_amdgcn_s_barrier();
      asm volatile("s_waitcnt lgkmcnt(0)");
      __builtin_amdgcn_sched_barrier(0);
      __builtin_amdgcn_s_setprio(1);
#pragma unroll
      for (int m = 0; m < 8; ++m) {
        acc[m][2] = __builtin_amdgcn_mfma_f32_16x16x32_bf16(a[m], b2, acc[m][2], 0, 0, 0);
        acc[m][3] = __builtin_amdgcn_mfma_f32_16x16x32_bf16(a[m], b3, acc[m][3], 0, 0, 0);
      }
      __builtin_amdgcn_s_setprio(0);
      if (t < nk - 2) {
        asm volatile("s_waitcnt vmcnt(6)" ::: "memory");
      } else if (t == nk - 2) {
        asm volatile("s_waitcnt vmcnt(0)" ::: "memory");
      }
      __builtin_amdgcn_sched_barrier(0);
      __builtin_amdgcn_s_barrier();
    }
  }

  // ---- epilogue ----
  const long m0 = (long)blockIdx.x * 256 + wr * 128;
  const long n0 = (long)blockIdx.y * 256 + wc * 64;
#pragma unroll
  for (int m = 0; m < 8; ++m) {
#pragma unroll
    for (int n = 0; n < 4; ++n) {
      const long mm = m0 + m * 16 + fq * 4;
      const long nn = n0 + n * 16 + fr;
      f32x4 v = acc[m][n];
      if (MODE == 0) {
        unsigned short* C = (unsigned short*)Cv + (long)bz * strideC;
        const float bb = bias[nn];
#pragma unroll
        for (int r = 0; r < 4; ++r) C[(mm + r) * ldc + nn] = f2bf(v[r] + bb);
      } else {
        float* C = (float*)Cv + (long)bz * strideC;
#pragma unroll
        for (int r = 0; r < 4; ++r) C[(mm + r) * ldc + nn] = v[r] * scale;
      }
    }
  }
}

// ---------------- 128x128 2-phase GEMM (kept for small shapes) ----------------
// MODE 1: bf16 out, +bias[row]   (V^T projection)
// MODE 2: f32 out, *scale        (PV)
template <int MODE>
__global__ __launch_bounds__(256) void gemm_bt(
    const unsigned short* __restrict__ A, long lda, long strideA,
    const unsigned short* __restrict__ BT, long ldb, long strideB,
    void* __restrict__ Cv, long ldc, long strideC,
    const float* __restrict__ bias, float scale, int K) {
  __shared__ unsigned short Ab[2][128 * 32];
  __shared__ unsigned short Bb[2][128 * 32];
  const int tid = threadIdx.x, wid = tid >> 6, lane = tid & 63;
  const int bz = blockIdx.z;
  A  += (long)bz * strideA + (long)blockIdx.x * 128 * lda;
  BT += (long)bz * strideB + (long)blockIdx.y * 128 * ldb;
  const int srow = lane >> 2;
  const int skk  = (lane & 3) * 8;

  auto stage = [&](int buf, int kt) {
    const unsigned short* As = A + (long)kt * 32;
    const unsigned short* Bs = BT + (long)kt * 32;
#pragma unroll
    for (int i = 0; i < 2; ++i) {
      int c = wid * 2 + i;
      async_copy16(As + (long)(c * 16 + srow) * lda + skk, &Ab[buf][c * 512]);
      async_copy16(Bs + (long)(c * 16 + srow) * ldb + skk, &Bb[buf][c * 512]);
    }
  };

  f32x4 acc[4][4] = {};
  const int nk = K / 32;
  stage(0, 0);
  __syncthreads();
  int buf = 0;
  const int wr = wid >> 1, wc = wid & 1;
  const int fr = lane & 15, fq = lane >> 4;
  for (int kt = 0; kt < nk; ++kt) {
    if (kt + 1 < nk) stage(buf ^ 1, kt + 1);
    const unsigned short* Ap = &Ab[buf][(wr * 64 + fr) * 32 + fq * 8];
    const unsigned short* Bp = &Bb[buf][(wc * 64 + fr) * 32 + fq * 8];
    bf16x8 af[4], bfv[4];
#pragma unroll
    for (int mi = 0; mi < 4; ++mi) af[mi] = *(const bf16x8*)(Ap + mi * 16 * 32);
#pragma unroll
    for (int ni = 0; ni < 4; ++ni) bfv[ni] = *(const bf16x8*)(Bp + ni * 16 * 32);
#pragma unroll
    for (int mi = 0; mi < 4; ++mi)
#pragma unroll
      for (int ni = 0; ni < 4; ++ni)
        acc[mi][ni] = __builtin_amdgcn_mfma_f32_16x16x32_bf16(af[mi], bfv[ni], acc[mi][ni], 0, 0, 0);
    __syncthreads();
    buf ^= 1;
  }

  const long m0 = (long)blockIdx.x * 128 + wr * 64;
  const long n0 = (long)blockIdx.y * 128 + wc * 64;
#pragma unroll
  for (int mi = 0; mi < 4; ++mi) {
#pragma unroll
    for (int ni = 0; ni < 4; ++ni) {
      const long m = m0 + mi * 16 + fq * 4;
      const long n = n0 + ni * 16 + fr;
      f32x4 v = acc[mi][ni];
      if (MODE == 1) {
        unsigned short* C = (unsigned short*)Cv + (long)bz * strideC;
#pragma unroll
        for (int r = 0; r < 4; ++r) C[(m + r) * ldc + n] = f2bf(v[r] + bias[m + r]);
      } else {
        float* C = (float*)Cv + (long)bz * strideC;
#pragma unroll
        for (int r = 0; r < 4; ++r) C[(m + r) * ldc + n] = v[r] * scale;
      }
    }
  }
}

// ---------------- masked row softmax + bf16 copy ----------------
__global__ __launch_bounds__(256) void softmax_rows(float* __restrict__ attn,
                                                    const int* __restrict__ mask,
                                                    unsigned short* __restrict__ attn_bf) {
  const int row = blockIdx.x;
  const int b = row >> 10;
  float* p = attn + (long)row * 1024;
  const int tid = threadIdx.x, lane = tid & 63, wid = tid >> 6;
  float4 v = ((const float4*)p)[tid];
  int4 mk = ((const int4*)(mask + b * 1024))[tid];
  v.x = mk.x ? v.x : -1e9f;
  v.y = mk.y ? v.y : -1e9f;
  v.z = mk.z ? v.z : -1e9f;
  v.w = mk.w ? v.w : -1e9f;
  float mx = fmaxf(fmaxf(v.x, v.y), fmaxf(v.z, v.w));
#pragma unroll
  for (int off = 32; off; off >>= 1) mx = fmaxf(mx, __shfl_xor(mx, off));
  __shared__ float red[4];
  if (lane == 0) red[wid] = mx;
  __syncthreads();
  mx = fmaxf(fmaxf(red[0], red[1]), fmaxf(red[2], red[3]));
  float e0 = __expf(v.x - mx), e1 = __expf(v.y - mx);
  float e2 = __expf(v.z - mx), e3 = __expf(v.w - mx);
  float s = e0 + e1 + e2 + e3;
#pragma unroll
  for (int off = 32; off; off >>= 1) s += __shfl_xor(s, off);
  __shared__ float red2[4];
  if (lane == 0) red2[wid] = s;
  __syncthreads();
  s = red2[0] + red2[1] + red2[2] + red2[3];
  const float inv = 1.0f / s;
  float4 o;
  o.x = e0 * inv; o.y = e1 * inv; o.z = e2 * inv; o.w = e3 * inv;
  ((float4*)p)[tid] = o;
  u16x4 ob;
  ob[0] = f2bf(o.x); ob[1] = f2bf(o.y); ob[2] = f2bf(o.z); ob[3] = f2bf(o.w);
  *(u16x4*)(attn_bf + (long)row * 1024 + tid * 4) = ob;
}

// ---------------- launch ----------------
extern "C" void kernel_launch(void* const* d_in, const int* in_sizes, int n_in,
                              void* d_out, int out_size, void* d_ws, size_t ws_size,
                              hipStream_t stream) {
  const float* emb = (const float*)d_in[0];
  const int* mask = (const int*)d_in[1];
  const int* isq = (const int*)d_in[2];
  const float* qWq = (const float*)d_in[3];  const float* qbq = (const float*)d_in[4];
  const float* qWk = (const float*)d_in[5];  const float* qbk = (const float*)d_in[6];
  const float* qWv = (const float*)d_in[7];  const float* qbv = (const float*)d_in[8];
  const float* dWq = (const float*)d_in[9];  const float* dbq = (const float*)d_in[10];
  const float* dWk = (const float*)d_in[11]; const float* dbk = (const float*)d_in[12];
  const float* dWv = (const float*)d_in[13]; const float* dbv = (const float*)d_in[14];

  char* ws = (char*)d_ws;
  unsigned short* emb_bf = (unsigned short*)ws;  ws += (size_t)16384 * 768 * 2;
  unsigned short* WT     = (unsigned short*)ws;  ws += (size_t)1792 * 768 * 2;
  float*          bias   = (float*)ws;           ws += (size_t)1792 * 4;
  unsigned short* QK     = (unsigned short*)ws;  ws += (size_t)16384 * 1536 * 2;
  unsigned short* VT     = (unsigned short*)ws;  ws += (size_t)256 * 16384 * 2;
  unsigned short* attnbf = (unsigned short*)ws;  ws += (size_t)16 * 1024 * 1024 * 2;

  float* out = (float*)d_out;                    // [16,1024,256]
  float* attn = out + (size_t)16 * 1024 * 256;   // [16,1024,1024]

  // allow 128 KiB dynamic LDS (idempotent; not a stream op -> capture-safe)
  (void)hipFuncSetAttribute((const void*)&gemm256<0>,
                            hipFuncAttributeMaxDynamicSharedMemorySize, 131072);
  (void)hipFuncSetAttribute((const void*)&gemm256<2>,
                            hipFuncAttributeMaxDynamicSharedMemorySize, 131072);

  hipLaunchKernelGGL(pack_emb, dim3(6144), dim3(256), 0, stream, emb, emb_bf);
  hipLaunchKernelGGL(pack_w, dim3(1792), dim3(256), 0, stream, isq,
                     qWq, qbq, qWk, qbk, qWv, qbv, dWq, dbq, dWk, dbk, dWv, dbv, WT, bias);
  // Q|K projection: [16384,1536] = emb_bf * WT^T + bias(col)  (256^2 8-phase)
  hipLaunchKernelGGL((gemm256<0>), dim3(64, 6, 1), dim3(512), 131072, stream,
                     emb_bf, 768L, 0L, WT, 768L, 0L, (void*)QK, 1536L, 0L, bias, 1.0f, 768);
  // V^T: [256,16384] = WvT * emb_bf^T + bias(row)  (128^2 kernel, better occupancy)
  hipLaunchKernelGGL((gemm_bt<1>), dim3(2, 128, 1), dim3(256), 0, stream,
                     WT + (size_t)1536 * 768, 768L, 0L, emb_bf, 768L, 0L,
                     (void*)VT, 16384L, 0L, bias + 1536, 1.0f, 768);
  // logits: per batch [1024,1024] = Q_b * K_b^T * invTemp  (256^2 8-phase)
  hipLaunchKernelGGL((gemm256<2>), dim3(4, 4, 16), dim3(512), 131072, stream,
                     QK, 1536L, (long)1024 * 1536, QK + 768, 1536L, (long)1024 * 1536,
                     (void*)attn, 1024L, (long)1024 * 1024, nullptr, INV_TEMP, 768);
  hipLaunchKernelGGL(softmax_rows, dim3(16384), dim3(256), 0, stream, attn, mask, attnbf);
  // out: per batch [1024,256] = attn_bf * V_b^T
  hipLaunchKernelGGL((gemm_bt<2>), dim3(8, 2, 16), dim3(256), 0, stream,
                     attnbf, 1024L, (long)1024 * 1024, VT, 16384L, 1024L,
                     (void*)out, 256L, (long)1024 * 256, nullptr, 1.0f, 1024);
}

// Round 3
// 163.268 us; speedup vs baseline: 1.2285x; 1.1229x over previous
//
#include <hip/hip_runtime.h>
#include <hip/hip_bf16.h>

// Problem constants: B=16, S=1024, D=768, DOUT=256
static constexpr float INV_TEMP = 0.03608439182435161f; // 1/sqrt(768)

typedef __attribute__((ext_vector_type(8))) short bf16x8;
typedef __attribute__((ext_vector_type(4))) float f32x4;
typedef __attribute__((ext_vector_type(8))) unsigned short u16x8;
typedef __attribute__((ext_vector_type(4))) unsigned short u16x4;

__device__ __forceinline__ unsigned short f2bf(float f) {
  unsigned u = __float_as_uint(f);
  u += 0x7fffu + ((u >> 16) & 1u);
  return (unsigned short)(u >> 16);
}

__device__ __forceinline__ void async_copy16(const void* g, void* lds) {
  __builtin_amdgcn_global_load_lds(
      (const __attribute__((address_space(1))) unsigned int*)g,
      (__attribute__((address_space(3))) unsigned int*)lds, 16, 0, 0);
}

// ---------------- pack kernels ----------------
__global__ __launch_bounds__(256) void pack_emb(const float* __restrict__ src,
                                                unsigned short* __restrict__ dst) {
  long i = ((long)blockIdx.x * 256 + threadIdx.x) * 8;
  float4 a = *(const float4*)(src + i);
  float4 b = *(const float4*)(src + i + 4);
  u16x8 v;
  v[0] = f2bf(a.x); v[1] = f2bf(a.y); v[2] = f2bf(a.z); v[3] = f2bf(a.w);
  v[4] = f2bf(b.x); v[5] = f2bf(b.y); v[6] = f2bf(b.z); v[7] = f2bf(b.w);
  *(u16x8*)(dst + i) = v;
}

__global__ __launch_bounds__(256) void pack_w(
    const int* __restrict__ isq_p,
    const float* qWq, const float* qbq, const float* qWk, const float* qbk,
    const float* qWv, const float* qbv,
    const float* dWq, const float* dbq, const float* dWk, const float* dbk,
    const float* dWv, const float* dbv,
    unsigned short* __restrict__ WT, float* __restrict__ bias) {
  const int n = blockIdx.x;  // 0..1791
  const int isq = *isq_p;
  const float* W; const float* bsrc; int col, srcN;
  if (n < 768)       { W = isq ? qWq : dWq; bsrc = isq ? qbq : dbq; col = n;        srcN = 768; }
  else if (n < 1536) { W = isq ? qWk : dWk; bsrc = isq ? qbk : dbk; col = n - 768;  srcN = 768; }
  else               { W = isq ? qWv : dWv; bsrc = isq ? qbv : dbv; col = n - 1536; srcN = 256; }
#pragma unroll
  for (int i = 0; i < 3; ++i) {
    int d = threadIdx.x + i * 256;
    WT[(long)n * 768 + d] = f2bf(W[(long)d * srcN + col]);
  }
  if (threadIdx.x == 0) bias[n] = bsrc[col];
}

// ============ shared 256x256 8-phase K-loop (T2+T3+T4+T5) ============
// LDS: [buf(2)][region: A0,A1,B0,B1][256 x 32] bf16 = 128 KiB.
// Reads per iter: ph0 4A+4B, ph1 4A, ph2 4A+4B, ph3 4A  (8/4/8/4).
// Stages per iter t: ph0 A1@t+1, ph1 B0@t+1 (buf (t+1)&1);
//                    ph2 A0@t+2, ph3 B1@t+2 (buf t&1).
// Each staged region's last ds_read is >=1 barrier before its stage issue.
// vmcnt(4) per tile end guarantees next tile fully landed (2 stages stay
// in flight); vmcnt(0) only at t==nk-2.
__device__ __forceinline__ void k_loop_256(
    const unsigned short* __restrict__ Apan, long lda,
    const unsigned short* __restrict__ Bpan, long ldb,
    int nk, unsigned short* smem, f32x4 (&acc)[8][4]) {
  const int tid = threadIdx.x;
  const int wid = tid >> 6, lane = tid & 63;
  const int wr = wid >> 2, wc = wid & 3;   // 2 (M) x 4 (N) wave grid
  const int fr = lane & 15, fq = lane >> 4;

  auto stage = [&](int tile, int mat, int ks, int buf) {
    const unsigned short* g = (mat ? Bpan : Apan) + (long)tile * 64 + ks * 32;
    const long ld = mat ? ldb : lda;
    unsigned short* d = smem + (((buf << 2) | (mat << 1) | ks) << 13);
#pragma unroll
    for (int i = 0; i < 2; ++i) {
      const int e = (tid + i * 512) * 8;     // elem offset in region
      const int row = e >> 5;                // 0..255
      const int sl = (e >> 3) & 3;           // 16B slot 0..3
      const int ss = sl ^ ((row >> 1) & 3);  // pre-swizzled source slot
      async_copy16(g + (long)row * ld + ss * 8, d + e);
    }
  };

  // per-lane swizzled read offset within a [256][32] region
  const int fro = fr * 32 + ((fq ^ ((fr >> 1) & 3)) << 3);
  const int awo = fro + (wr * 128) * 32;
  const int bwo = fro + (wc * 64) * 32;

  // prologue: tile0 (A0,B0,A1,B1) + tile1 (A0,B1)
  stage(0, 0, 0, 0); stage(0, 1, 0, 0); stage(0, 0, 1, 0); stage(0, 1, 1, 0);
  if (nk > 1) {
    stage(1, 0, 0, 1); stage(1, 1, 1, 1);
    asm volatile("s_waitcnt vmcnt(4)" ::: "memory");
  } else {
    asm volatile("s_waitcnt vmcnt(0)" ::: "memory");
  }
  __builtin_amdgcn_sched_barrier(0);
  __builtin_amdgcn_s_barrier();

  for (int t = 0; t < nk; ++t) {
    const int p = t & 1;
    const unsigned short* A0 = smem + (((p << 2) | 0) << 13);
    const unsigned short* A1 = smem + (((p << 2) | 1) << 13);
    const unsigned short* B0 = smem + (((p << 2) | 2) << 13);
    const unsigned short* B1 = smem + (((p << 2) | 3) << 13);
    bf16x8 a[4], b[4];

    // ---- phase 0: ksub0, m0..3 x n0..3 ----
#pragma unroll
    for (int m = 0; m < 4; ++m) a[m] = *(const bf16x8*)(A0 + awo + m * 512);
#pragma unroll
    for (int n = 0; n < 4; ++n) b[n] = *(const bf16x8*)(B0 + bwo + n * 512);
    if (t + 1 < nk) stage(t + 1, 0, 1, (t + 1) & 1);  // A1@t+1
    __builtin_amdgcn_s_barrier();
    asm volatile("s_waitcnt lgkmcnt(0)");
    __builtin_amdgcn_sched_barrier(0);
    __builtin_amdgcn_s_setprio(1);
#pragma unroll
    for (int m = 0; m < 4; ++m)
#pragma unroll
      for (int n = 0; n < 4; ++n)
        acc[m][n] = __builtin_amdgcn_mfma_f32_16x16x32_bf16(a[m], b[n], acc[m][n], 0, 0, 0);
    __builtin_amdgcn_s_setprio(0);
    __builtin_amdgcn_sched_barrier(0);
    __builtin_amdgcn_s_barrier();

    // ---- phase 1: ksub0, m4..7 x n0..3 (b reused) ----
#pragma unroll
    for (int m = 0; m < 4; ++m) a[m] = *(const bf16x8*)(A0 + awo + (4 + m) * 512);
    if (t + 1 < nk) stage(t + 1, 1, 0, (t + 1) & 1);  // B0@t+1
    __builtin_amdgcn_s_barrier();
    asm volatile("s_waitcnt lgkmcnt(0)");
    __builtin_amdgcn_sched_barrier(0);
    __builtin_amdgcn_s_setprio(1);
#pragma unroll
    for (int m = 0; m < 4; ++m)
#pragma unroll
      for (int n = 0; n < 4; ++n)
        acc[4 + m][n] = __builtin_amdgcn_mfma_f32_16x16x32_bf16(a[m], b[n], acc[4 + m][n], 0, 0, 0);
    __builtin_amdgcn_s_setprio(0);
    __builtin_amdgcn_sched_barrier(0);
    __builtin_amdgcn_s_barrier();

    // ---- phase 2: ksub1, m0..3 x n0..3 ----
#pragma unroll
    for (int m = 0; m < 4; ++m) a[m] = *(const bf16x8*)(A1 + awo + m * 512);
#pragma unroll
    for (int n = 0; n < 4; ++n) b[n] = *(const bf16x8*)(B1 + bwo + n * 512);
    if (t + 2 < nk) stage(t + 2, 0, 0, p);  // A0@t+2
    __builtin_amdgcn_s_barrier();
    asm volatile("s_waitcnt lgkmcnt(0)");
    __builtin_amdgcn_sched_barrier(0);
    __builtin_amdgcn_s_setprio(1);
#pragma unroll
    for (int m = 0; m < 4; ++m)
#pragma unroll
      for (int n = 0; n < 4; ++n)
        acc[m][n] = __builtin_amdgcn_mfma_f32_16x16x32_bf16(a[m], b[n], acc[m][n], 0, 0, 0);
    __builtin_amdgcn_s_setprio(0);
    __builtin_amdgcn_sched_barrier(0);
    __builtin_amdgcn_s_barrier();

    // ---- phase 3: ksub1, m4..7 x n0..3 + tile-end counted vmcnt ----
#pragma unroll
    for (int m = 0; m < 4; ++m) a[m] = *(const bf16x8*)(A1 + awo + (4 + m) * 512);
    if (t + 2 < nk) stage(t + 2, 1, 1, p);  // B1@t+2
    __builtin_amdgcn_s_barrier();
    asm volatile("s_waitcnt lgkmcnt(0)");
    __builtin_amdgcn_sched_barrier(0);
    __builtin_amdgcn_s_setprio(1);
#pragma unroll
    for (int m = 0; m < 4; ++m)
#pragma unroll
      for (int n = 0; n < 4; ++n)
        acc[4 + m][n] = __builtin_amdgcn_mfma_f32_16x16x32_bf16(a[m], b[n], acc[4 + m][n], 0, 0, 0);
    __builtin_amdgcn_s_setprio(0);
    if (t < nk - 2) {
      asm volatile("s_waitcnt vmcnt(4)" ::: "memory");
    } else if (t == nk - 2) {
      asm volatile("s_waitcnt vmcnt(0)" ::: "memory");
    }
    __builtin_amdgcn_sched_barrier(0);
    __builtin_amdgcn_s_barrier();
  }
}

// ============ merged projection dispatch: QK (384 blocks) + VT (64 blocks) ============
__global__ __launch_bounds__(512, 2) void proj256(
    const unsigned short* __restrict__ emb_bf,
    const unsigned short* __restrict__ WT,
    const float* __restrict__ bias,
    unsigned short* __restrict__ QK,
    unsigned short* __restrict__ VT) {
  extern __shared__ unsigned short smem[];
  const int id = blockIdx.x;
  const unsigned short* Apan;
  const unsigned short* Bpan;
  if (id < 384) {  // QK tile: rows = emb seq, cols = Wq|Wk outputs
    Apan = emb_bf + (long)(id & 63) * 256 * 768;
    Bpan = WT + (long)(id >> 6) * 256 * 768;
  } else {         // VT tile: rows = DOUT (WvT), cols = emb seq
    Apan = WT + (long)1536 * 768;
    Bpan = emb_bf + (long)(id - 384) * 256 * 768;
  }
  f32x4 acc[8][4];
#pragma unroll
  for (int m = 0; m < 8; ++m)
#pragma unroll
    for (int n = 0; n < 4; ++n) acc[m][n] = f32x4{0.f, 0.f, 0.f, 0.f};

  k_loop_256(Apan, 768, Bpan, 768, 12, smem, acc);

  const int wid = threadIdx.x >> 6, lane = threadIdx.x & 63;
  const int wr = wid >> 2, wc = wid & 3;
  const int fr = lane & 15, fq = lane >> 4;
  if (id < 384) {
    const long x = id & 63, y = id >> 6;
#pragma unroll
    for (int m = 0; m < 8; ++m)
#pragma unroll
      for (int n = 0; n < 4; ++n) {
        const long mm = x * 256 + wr * 128 + m * 16 + fq * 4;
        const long nn = y * 256 + wc * 64 + n * 16 + fr;
        const float bb = bias[nn];
        f32x4 v = acc[m][n];
#pragma unroll
        for (int r = 0; r < 4; ++r) QK[(mm + r) * 1536 + nn] = f2bf(v[r] + bb);
      }
  } else {
    const long v0 = id - 384;
#pragma unroll
    for (int m = 0; m < 8; ++m)
#pragma unroll
      for (int n = 0; n < 4; ++n) {
        const long mm = wr * 128 + m * 16 + fq * 4;   // DOUT row 0..255
        const long nn = v0 * 256 + wc * 64 + n * 16 + fr;
        f32x4 v = acc[m][n];
#pragma unroll
        for (int r = 0; r < 4; ++r)
          VT[(mm + r) * 16384 + nn] = f2bf(v[r] + bias[1536 + mm + r]);
      }
  }
}

// ============ logits: per-batch Q*K^T * invTemp -> f32 attn ============
__global__ __launch_bounds__(512, 2) void logits256(
    const unsigned short* __restrict__ QK, float* __restrict__ attn) {
  extern __shared__ unsigned short smem[];
  const int bz = blockIdx.z;
  const unsigned short* Apan = QK + (long)bz * 1024 * 1536 + (long)blockIdx.x * 256 * 1536;
  const unsigned short* Bpan = QK + 768 + (long)bz * 1024 * 1536 + (long)blockIdx.y * 256 * 1536;
  f32x4 acc[8][4];
#pragma unroll
  for (int m = 0; m < 8; ++m)
#pragma unroll
    for (int n = 0; n < 4; ++n) acc[m][n] = f32x4{0.f, 0.f, 0.f, 0.f};

  k_loop_256(Apan, 1536, Bpan, 1536, 12, smem, acc);

  const int wid = threadIdx.x >> 6, lane = threadIdx.x & 63;
  const int wr = wid >> 2, wc = wid & 3;
  const int fr = lane & 15, fq = lane >> 4;
  float* C = attn + (long)bz * 1024 * 1024;
#pragma unroll
  for (int m = 0; m < 8; ++m)
#pragma unroll
    for (int n = 0; n < 4; ++n) {
      const long mm = (long)blockIdx.x * 256 + wr * 128 + m * 16 + fq * 4;
      const long nn = (long)blockIdx.y * 256 + wc * 64 + n * 16 + fr;
      f32x4 v = acc[m][n];
#pragma unroll
      for (int r = 0; r < 4; ++r) C[(mm + r) * 1024 + nn] = v[r] * INV_TEMP;
    }
}

// ============ PV: 128x64 tiles, 512 blocks, 2+ blocks/CU overlap ============
__global__ __launch_bounds__(256) void gemm_pv(
    const unsigned short* __restrict__ attnbf,   // [16][1024][1024]
    const unsigned short* __restrict__ VT,       // [256][16384]
    float* __restrict__ out) {                   // [16][1024][256]
  __shared__ unsigned short Ab[2][128 * 32];
  __shared__ unsigned short Bb[2][64 * 32];
  const int tid = threadIdx.x, wid = tid >> 6, lane = tid & 63;
  const int bz = blockIdx.z;
  const unsigned short* A = attnbf + (long)bz * 1024 * 1024 + (long)blockIdx.x * 128 * 1024;
  const unsigned short* BT = VT + (long)bz * 1024 + (long)blockIdx.y * 64 * 16384;
  const int srow = lane >> 2;
  const int skk = (lane & 3) * 8;

  auto stage = [&](int buf, int kt) {
    const unsigned short* As = A + (long)kt * 32;
    const unsigned short* Bs = BT + (long)kt * 32;
#pragma unroll
    for (int i = 0; i < 2; ++i) {
      int c = wid * 2 + i;  // A chunks 0..7
      async_copy16(As + (long)(c * 16 + srow) * 1024 + skk, &Ab[buf][c * 512]);
    }
    async_copy16(Bs + (long)(wid * 16 + srow) * 16384 + skk, &Bb[buf][wid * 512]);
  };

  f32x4 acc[4][2] = {};
  const int nk = 32;  // K = 1024
  stage(0, 0);
  __syncthreads();
  int buf = 0;
  const int wr = wid >> 1, wc = wid & 1;
  const int fr = lane & 15, fq = lane >> 4;
  for (int kt = 0; kt < nk; ++kt) {
    if (kt + 1 < nk) stage(buf ^ 1, kt + 1);
    const unsigned short* Ap = &Ab[buf][(wr * 64 + fr) * 32 + fq * 8];
    const unsigned short* Bp = &Bb[buf][(wc * 32 + fr) * 32 + fq * 8];
    bf16x8 af[4], bfv[2];
#pragma unroll
    for (int mi = 0; mi < 4; ++mi) af[mi] = *(const bf16x8*)(Ap + mi * 16 * 32);
#pragma unroll
    for (int ni = 0; ni < 2; ++ni) bfv[ni] = *(const bf16x8*)(Bp + ni * 16 * 32);
#pragma unroll
    for (int mi = 0; mi < 4; ++mi)
#pragma unroll
      for (int ni = 0; ni < 2; ++ni)
        acc[mi][ni] = __builtin_amdgcn_mfma_f32_16x16x32_bf16(af[mi], bfv[ni], acc[mi][ni], 0, 0, 0);
    __syncthreads();
    buf ^= 1;
  }

  float* C = out + (long)bz * 1024 * 256;
  const long m0 = (long)blockIdx.x * 128 + wr * 64;
  const long n0 = (long)blockIdx.y * 64 + wc * 32;
#pragma unroll
  for (int mi = 0; mi < 4; ++mi)
#pragma unroll
    for (int ni = 0; ni < 2; ++ni) {
      const long m = m0 + mi * 16 + fq * 4;
      const long n = n0 + ni * 16 + fr;
      f32x4 v = acc[mi][ni];
#pragma unroll
      for (int r = 0; r < 4; ++r) C[(m + r) * 256 + n] = v[r];
    }
}

// ---------------- masked row softmax + bf16 copy ----------------
__global__ __launch_bounds__(256) void softmax_rows(float* __restrict__ attn,
                                                    const int* __restrict__ mask,
                                                    unsigned short* __restrict__ attn_bf) {
  const int row = blockIdx.x;
  const int b = row >> 10;
  float* p = attn + (long)row * 1024;
  const int tid = threadIdx.x, lane = tid & 63, wid = tid >> 6;
  float4 v = ((const float4*)p)[tid];
  int4 mk = ((const int4*)(mask + b * 1024))[tid];
  v.x = mk.x ? v.x : -1e9f;
  v.y = mk.y ? v.y : -1e9f;
  v.z = mk.z ? v.z : -1e9f;
  v.w = mk.w ? v.w : -1e9f;
  float mx = fmaxf(fmaxf(v.x, v.y), fmaxf(v.z, v.w));
#pragma unroll
  for (int off = 32; off; off >>= 1) mx = fmaxf(mx, __shfl_xor(mx, off));
  __shared__ float red[4];
  if (lane == 0) red[wid] = mx;
  __syncthreads();
  mx = fmaxf(fmaxf(red[0], red[1]), fmaxf(red[2], red[3]));
  float e0 = __expf(v.x - mx), e1 = __expf(v.y - mx);
  float e2 = __expf(v.z - mx), e3 = __expf(v.w - mx);
  float s = e0 + e1 + e2 + e3;
#pragma unroll
  for (int off = 32; off; off >>= 1) s += __shfl_xor(s, off);
  __shared__ float red2[4];
  if (lane == 0) red2[wid] = s;
  __syncthreads();
  s = red2[0] + red2[1] + red2[2] + red2[3];
  const float inv = 1.0f / s;
  float4 o;
  o.x = e0 * inv; o.y = e1 * inv; o.z = e2 * inv; o.w = e3 * inv;
  ((float4*)p)[tid] = o;
  u16x4 ob;
  ob[0] = f2bf(o.x); ob[1] = f2bf(o.y); ob[2] = f2bf(o.z); ob[3] = f2bf(o.w);
  *(u16x4*)(attn_bf + (long)row * 1024 + tid * 4) = ob;
}

// ---------------- launch ----------------
extern "C" void kernel_launch(void* const* d_in, const int* in_sizes, int n_in,
                              void* d_out, int out_size, void* d_ws, size_t ws_size,
                              hipStream_t stream) {
  const float* emb = (const float*)d_in[0];
  const int* mask = (const int*)d_in[1];
  const int* isq = (const int*)d_in[2];
  const float* qWq = (const float*)d_in[3];  const float* qbq = (const float*)d_in[4];
  const float* qWk = (const float*)d_in[5];  const float* qbk = (const float*)d_in[6];
  const float* qWv = (const float*)d_in[7];  const float* qbv = (const float*)d_in[8];
  const float* dWq = (const float*)d_in[9];  const float* dbq = (const float*)d_in[10];
  const float* dWk = (const float*)d_in[11]; const float* dbk = (const float*)d_in[12];
  const float* dWv = (const float*)d_in[13]; const float* dbv = (const float*)d_in[14];

  char* ws = (char*)d_ws;
  unsigned short* emb_bf = (unsigned short*)ws;  ws += (size_t)16384 * 768 * 2;
  unsigned short* WT     = (unsigned short*)ws;  ws += (size_t)1792 * 768 * 2;
  float*          bias   = (float*)ws;           ws += (size_t)1792 * 4;
  unsigned short* QK     = (unsigned short*)ws;  ws += (size_t)16384 * 1536 * 2;
  unsigned short* VT     = (unsigned short*)ws;  ws += (size_t)256 * 16384 * 2;
  unsigned short* attnbf = (unsigned short*)ws;  ws += (size_t)16 * 1024 * 1024 * 2;

  float* out = (float*)d_out;                    // [16,1024,256]
  float* attn = out + (size_t)16 * 1024 * 256;   // [16,1024,1024]

  (void)hipFuncSetAttribute((const void*)&proj256,
                            hipFuncAttributeMaxDynamicSharedMemorySize, 131072);
  (void)hipFuncSetAttribute((const void*)&logits256,
                            hipFuncAttributeMaxDynamicSharedMemorySize, 131072);

  hipLaunchKernelGGL(pack_emb, dim3(6144), dim3(256), 0, stream, emb, emb_bf);
  hipLaunchKernelGGL(pack_w, dim3(1792), dim3(256), 0, stream, isq,
                     qWq, qbq, qWk, qbk, qWv, qbv, dWq, dbq, dWk, dbk, dWv, dbv, WT, bias);
  // merged Q|K projection (blocks 0..383) + V^T projection (blocks 384..447)
  hipLaunchKernelGGL(proj256, dim3(448), dim3(512), 131072, stream,
                     emb_bf, WT, bias, QK, VT);
  // logits: per batch [1024,1024] = Q_b * K_b^T * invTemp -> d_out attn (f32)
  hipLaunchKernelGGL(logits256, dim3(4, 4, 16), dim3(512), 131072, stream, QK, attn);
  hipLaunchKernelGGL(softmax_rows, dim3(16384), dim3(256), 0, stream, attn, mask, attnbf);
  // out: per batch [1024,256] = attn_bf * V_b^T  (128x64 tiles, 512 blocks)
  hipLaunchKernelGGL(gemm_pv, dim3(8, 4, 16), dim3(256), 0, stream, attnbf, VT, out);
}